// Round 12
// baseline (203.973 us; speedup 1.0000x reference)
//
#include <hip/hip_runtime.h>
#include <hip/hip_bf16.h>

typedef __attribute__((ext_vector_type(8))) short bf16x8;
typedef __attribute__((ext_vector_type(4))) float f32x4;
typedef __attribute__((ext_vector_type(2))) float f32x2;
typedef __attribute__((ext_vector_type(4))) unsigned short u16x4;

#define NEGINF (-3.4028234663852886e38f)
#define BIGP (1 << 20)

__device__ __forceinline__ unsigned short f2b(float f) {
    union { float f; unsigned u; } x; x.f = f;
    unsigned r = x.u + 0x7FFFu + ((x.u >> 16) & 1u);
    return (unsigned short)(r >> 16);
}
__device__ __forceinline__ float b2f(unsigned short b) {
    union { unsigned u; float f; } x; x.u = ((unsigned)b) << 16;
    return x.f;
}
__device__ __forceinline__ void load_lds16(const void* g, void* l) {
    __builtin_amdgcn_global_load_lds((const __attribute__((address_space(1))) void*)g,
                                     (__attribute__((address_space(3))) void*)l, 16, 0, 0);
}
__device__ __forceinline__ int swzf(int r) { return (r & 15) ^ (r >> 4); }

// ======== MFMA compute core (R5/R6/R7-verified): swzf-swizzled As/Bs [64][128] ========
#define GEMM_COMPUTE(as, bs)                                                        \
    _Pragma("unroll")                                                               \
    for (int ks = 0; ks < 4; ++ks) {                                                \
        int kc = ks * 4 + rsub;                                                     \
        bf16x8 af[2], bfr[2];                                                       \
        _Pragma("unroll")                                                           \
        for (int mi = 0; mi < 2; ++mi) {                                            \
            int rr = wr * 32 + mi * 16 + c_lin;                                     \
            af[mi] = *(const bf16x8*)((as) + rr * 128 + ((kc ^ c_lin ^ (wr * 2 + mi)) << 3)); \
        }                                                                           \
        _Pragma("unroll")                                                           \
        for (int nj = 0; nj < 2; ++nj) {                                            \
            int rr = wc * 32 + nj * 16 + c_lin;                                     \
            bfr[nj] = *(const bf16x8*)((bs) + rr * 128 + ((kc ^ c_lin ^ (wc * 2 + nj)) << 3)); \
        }                                                                           \
        _Pragma("unroll")                                                           \
        for (int mi = 0; mi < 2; ++mi)                                              \
            _Pragma("unroll")                                                       \
            for (int nj = 0; nj < 2; ++nj)                                          \
                acc[mi][nj] = __builtin_amdgcn_mfma_f32_16x16x32_bf16(              \
                    af[mi], bfr[nj], acc[mi][nj], 0, 0, 0);                         \
    }

// ================= W_pe: WpeT[j][h] = (proj @ enc)^T bf16, single-buffered (R6/R7-verified) =================
__device__ __forceinline__ void wpe_body(const float* __restrict__ proj,
                                         const float* __restrict__ enc,
                                         unsigned short* __restrict__ WpeT,
                                         int bx, int by,
                                         unsigned short* AsB, unsigned short* BsB) {
    const int KR = 750;
    const int tid = threadIdx.x;
    const int wid = tid >> 6, lane = tid & 63;
    const int m0 = by * 64, n0 = bx * 64;
    const int wr = wid >> 1, wc = wid & 1;
    const int c_lin = lane & 15, rsub = lane >> 4;
    const int tn = (tid & 15) * 4, tc = tid >> 4;

    f32x4 acc[2][2];
    const f32x4 zero = {0.f, 0.f, 0.f, 0.f};
#pragma unroll
    for (int mi = 0; mi < 2; ++mi)
#pragma unroll
        for (int nj = 0; nj < 2; ++nj) acc[mi][nj] = zero;

    for (int t = 0; t < 6; ++t) {
        int kt = t << 7;
        float va[4][8];
#pragma unroll
        for (int p = 0; p < 4; ++p) {
            int r = m0 + p * 16 + tc;
#pragma unroll
            for (int e = 0; e < 4; ++e) {
                int d = kt + (tid & 15) * 8 + e * 2;
                int dcl = min(d, KR - 2);
                f32x2 t2 = *(const f32x2*)(proj + (size_t)r * KR + dcl);
                va[p][e * 2]     = (d < KR) ? t2[0] : 0.f;
                va[p][e * 2 + 1] = (d + 1 < KR) ? t2[1] : 0.f;
            }
        }
        f32x4 vb[8];
        int nbl = n0 + tn;
        int n1 = min(nbl, 748), n2 = min(nbl + 2, 748);
#pragma unroll
        for (int p = 0; p < 8; ++p) {
            int kg = min(kt + tc * 8 + p, KR - 1);
            const float* rowp = enc + (size_t)kg * KR;
            f32x2 a = *(const f32x2*)(rowp + n1);
            f32x2 b = *(const f32x2*)(rowp + n2);
            f32x4 tv; tv[0] = a[0]; tv[1] = a[1]; tv[2] = b[0]; tv[3] = b[1];
            vb[p] = tv;
        }
        __syncthreads();
#pragma unroll
        for (int p = 0; p < 4; ++p) {
            int r = p * 16 + tc;
            bf16x8 w;
#pragma unroll
            for (int e = 0; e < 8; ++e) w[e] = (short)f2b(va[p][e]);
            *(bf16x8*)(AsB + r * 128 + (((tid & 15) ^ swzf(r)) << 3)) = w;
        }
#pragma unroll
        for (int q = 0; q < 4; ++q) {
            int row = tn + q;
            bf16x8 w;
#pragma unroll
            for (int p = 0; p < 8; ++p) w[p] = (short)f2b(vb[p][q]);
            *(bf16x8*)(BsB + row * 128 + ((tc ^ swzf(row)) << 3)) = w;
        }
        __syncthreads();
        const unsigned short* as = AsB;
        const unsigned short* bs = BsB;
        GEMM_COMPUTE(as, bs)
    }
#pragma unroll
    for (int mi = 0; mi < 2; ++mi) {
        int hb = m0 + wr * 32 + mi * 16 + rsub * 4;
#pragma unroll
        for (int nj = 0; nj < 2; ++nj) {
            int j = n0 + wc * 32 + nj * 16 + c_lin;
#pragma unroll
            for (int i = 0; i < 4; ++i)
                WpeT[(size_t)j * 768 + hb + i] = f2b(acc[mi][nj][i]);
        }
    }
}

// ===== L0: W_pe only (144 blocks) — isolated so its VGPR/LDS can't pollute pool =====
__global__ __launch_bounds__(256) void l0_wpe_k(const float* __restrict__ proj_w,
                                                const float* __restrict__ enc_w,
                                                unsigned short* __restrict__ WpeT) {
    __shared__ __align__(16) char smem[32768];
    int r = blockIdx.x;
    wpe_body(proj_w, enc_w, WpeT, r % 12, r / 12,
             (unsigned short*)smem, (unsigned short*)(smem + 16384));
}

// ================= transpose tile 32x32, 8B stores (R4-verified) =================
__device__ __forceinline__ void trans32(const float* __restrict__ in, int K, int N,
                                        unsigned short* __restrict__ out, int ldo,
                                        int bx, int by, int tid, float (*tile)[33]) {
    int n0 = bx * 32, k0 = by * 32;
    int tx = tid & 31, ty = tid >> 5;
#pragma unroll
    for (int i = 0; i < 4; ++i) {
        int k = k0 + ty * 4 + i, n = n0 + tx;
        tile[ty * 4 + i][tx] = (k < K && n < N) ? in[(size_t)k * N + n] : 0.f;
    }
    __syncthreads();
    int n = tid >> 3, kc = tid & 7;
    u16x4 o;
#pragma unroll
    for (int q = 0; q < 4; ++q) o[q] = f2b(tile[kc * 4 + q][n]);
    *(u16x4*)(out + (size_t)(n0 + n) * ldo + k0 + kc * 4) = o;
}

// ===== L1 block map (counts): pool 2048 | scan 64 | cit 256 | bpe 3 | w1T 4608 | w2T 9216 =====
#define L1_POOL 2048
#define L1_SCAN 64
#define L1_CIT  256
#define L1_BPE  3
#define L1_W1T  4608
#define L1_W2T  9216
#define L1_TOTAL (L1_POOL + L1_SCAN + L1_CIT + L1_BPE + L1_W1T + L1_W2T)

__global__ __launch_bounds__(256) void pool_mega_k(
    const int* __restrict__ tokens, const float* __restrict__ hs,
    int* __restrict__ meta, unsigned short* __restrict__ citA,
    float* __restrict__ part,
    const float* __restrict__ proj_b, const float* __restrict__ enc_w,
    const float* __restrict__ enc_b,
    const float* __restrict__ w1, const float* __restrict__ w2,
    float* __restrict__ bpe,
    unsigned short* __restrict__ w1T, unsigned short* __restrict__ w2T) {
    __shared__ float tile[32][33];
    int bid = blockIdx.x, tid = threadIdx.x;
    if (bid < L1_POOL) {
        // pool with inline '@' ballot scan (R6/R8/R9-verified)
        if (tid >= 192) return;
        int b = bid >> 3, ch = bid & 7;
        int lane = tid & 63;
        const int* row = tokens + (size_t)b * 512;
        int first = BIGP, second = BIGP;
#pragma unroll
        for (int c = 0; c < 8; ++c) {
            int tok = row[c * 64 + lane];
            unsigned long long m = __ballot(tok == 5);
            if (m) {
                int base = c * 64;
                if (first == BIGP) {
                    first = base + (int)__ffsll(m) - 1;
                    unsigned long long m2 = m & (m - 1);
                    if (m2) second = base + (int)__ffsll(m2) - 1;
                } else if (second == BIGP) {
                    second = base + (int)__ffsll(m) - 1;
                }
            }
        }
        int start, end;
        if (second < BIGP) { start = first; end = second; }
        else               { start = 0;     end = 512;    }
        f32x4 m = { NEGINF, NEGINF, NEGINF, NEGINF };
        const float* basep = hs + (size_t)b * 512 * 768 + tid * 4;
        int s0 = ch * 64, hi = s0 + 64;
        int e1 = min(start, hi);
        int s2 = max(end + 1, s0);
#pragma unroll 4
        for (int s = s0; s < e1; ++s) {
            f32x4 v = *(const f32x4*)(basep + (size_t)s * 768);
#pragma unroll
            for (int j = 0; j < 4; ++j) m[j] = fmaxf(m[j], v[j]);
        }
#pragma unroll 4
        for (int s = s2; s < hi; ++s) {
            f32x4 v = *(const f32x4*)(basep + (size_t)s * 768);
#pragma unroll
            for (int j = 0; j < 4; ++j) m[j] = fmaxf(m[j], v[j]);
        }
        *(f32x4*)(part + ((size_t)b * 8 + ch) * 768 + tid * 4) = m;
        return;
    }
    if (bid < L1_POOL + L1_SCAN) {
        // meta scan: one wave per batch row (R4-verified)
        const int S = 512;
        int b = (bid - L1_POOL) * 4 + (tid >> 6), l = tid & 63;
        const int* row = tokens + (size_t)b * S;
        int base = l * 8;
        int toks[8];
#pragma unroll
        for (int i = 0; i < 8; ++i) toks[i] = row[base + i];
        int am = 0, cnt = 0, minAt = BIGP, minC = BIGP;
#pragma unroll
        for (int i = 0; i < 8; ++i) {
            if (toks[i] == 5) { am |= 1 << i; cnt++; if (base + i < minAt) minAt = base + i; }
            if (toks[i] == 7) { if (base + i < minC) minC = base + i; }
        }
        for (int off = 1; off < 64; off <<= 1) {
            minAt = min(minAt, __shfl_xor(minAt, off));
            minC  = min(minC,  __shfl_xor(minC,  off));
            cnt  += __shfl_xor(cnt, off);
        }
        int first = minAt, minAt2 = BIGP;
#pragma unroll
        for (int i = 0; i < 8; ++i)
            if ((am >> i) & 1) { int idx = base + i; if (idx > first && idx < minAt2) minAt2 = idx; }
        for (int off = 1; off < 64; off <<= 1) minAt2 = min(minAt2, __shfl_xor(minAt2, off));
        if (l == 0) {
            int ge2 = (cnt >= 2) ? 1 : 0;
            int start = ge2 ? first : 0;
            int end = ge2 ? minAt2 : S;
            int anyKeep = (ge2 && (start > 0 || end < S - 1)) ? 1 : 0;
            int has_c = (minC < S) ? 1 : 0;
            int cpos = min(minC, S - 1);
            int* m = meta + b * 6;
            m[0] = start; m[1] = end; m[2] = cpos; m[3] = has_c; m[4] = anyKeep; m[5] = 0;
        }
        return;
    }
    if (bid < L1_POOL + L1_SCAN + L1_CIT) {
        // cit gather with inline CITSEG ballot scan (R6/R9-verified)
        if (tid >= 192) return;
        int b = bid - (L1_POOL + L1_SCAN), lane = tid & 63;
        const int* row = tokens + (size_t)b * 512;
        int minC = BIGP;
#pragma unroll
        for (int c = 0; c < 8; ++c) {
            int tok = row[c * 64 + lane];
            unsigned long long m = __ballot(tok == 7);
            if (minC == BIGP && m) minC = c * 64 + (int)__ffsll(m) - 1;
        }
        int cpos = min(minC, 511);
        f32x4 cv = *(const f32x4*)(hs + ((size_t)b * 512 + cpos) * 768 + tid * 4);
        u16x4 co;
#pragma unroll
        for (int j = 0; j < 4; ++j) co[j] = f2b(cv[j]);
        *(u16x4*)(citA + (size_t)b * 768 + tid * 4) = co;
        return;
    }
    if (bid < L1_POOL + L1_SCAN + L1_CIT + L1_BPE) {
        // b_pe[j] = proj_b . enc[:,j] + enc_b[j] (coalesced across j)
        int j = (bid - (L1_POOL + L1_SCAN + L1_CIT)) * 256 + tid;
        if (j < 750) {
            float a = enc_b[j];
            for (int d = 0; d < 750; ++d) a += proj_b[d] * enc_w[(size_t)d * 750 + j];
            bpe[j] = a;
        }
        return;
    }
    int r = bid - (L1_POOL + L1_SCAN + L1_CIT + L1_BPE);
    if (r < L1_W1T) { trans32(w1, 1518, 3036, w1T, 1536, r % 96, r / 96, tid, tile); return; }
    r -= L1_W1T;
    trans32(w2, 3036, 3036, w2T, 3072, r % 96, r / 96, tid, tile);
}

// ================= G12 body (R5/R6/R7-verified): cit_enc = has_c ? citA@WpeT^T + bpe : enc_b =================
__device__ __forceinline__ void g12_body(
    const unsigned short* __restrict__ A, const unsigned short* __restrict__ Bt,
    const float* __restrict__ bpe, const float* __restrict__ encb,
    const int* __restrict__ meta, unsigned short* __restrict__ X,
    int bx, int by, unsigned short* AsB, unsigned short* BsB) {
    const int lda = 768, ldb = 768, ldx = 1536, Nreal = 750;
    const int tid = threadIdx.x;
    const int wid = tid >> 6, lane = tid & 63;
    const int m0 = by * 64, n0 = bx * 64;
    const int wr = wid >> 1, wc = wid & 1;
    const int c_lin = lane & 15, rsub = lane >> 4;

    int aoff[4], boff[4], ldst[4];
#pragma unroll
    for (int i = 0; i < 4; ++i) {
        int r = wid * 16 + i * 4 + rsub;
        int csrc = (c_lin ^ swzf(r)) << 3;
        aoff[i] = (m0 + r) * lda + csrc;
        boff[i] = (n0 + r) * ldb + csrc;
        ldst[i] = (wid * 16 + i * 4) * 128;
    }
    f32x4 acc[2][2];
    const f32x4 zero = {0.f, 0.f, 0.f, 0.f};
#pragma unroll
    for (int mi = 0; mi < 2; ++mi)
#pragma unroll
        for (int nj = 0; nj < 2; ++nj) acc[mi][nj] = zero;

    auto stage = [&](int nb, int kt) {
#pragma unroll
        for (int i = 0; i < 4; ++i) load_lds16(A + aoff[i] + kt, AsB + nb * 8192 + ldst[i]);
#pragma unroll
        for (int i = 0; i < 4; ++i) load_lds16(Bt + boff[i] + kt, BsB + nb * 8192 + ldst[i]);
    };
    const int nt = 6;
    stage(0, 0);
    int cb = 0;
    for (int t = 0; t < nt; ++t) {
        __syncthreads();
        if (t + 1 < nt) stage(cb ^ 1, (t + 1) << 7);
        const unsigned short* as = AsB + cb * 8192;
        const unsigned short* bs = BsB + cb * 8192;
        GEMM_COMPUTE(as, bs)
        cb ^= 1;
    }
#pragma unroll
    for (int mi = 0; mi < 2; ++mi) {
        int rowb = m0 + wr * 32 + mi * 16 + rsub * 4;
#pragma unroll
        for (int nj = 0; nj < 2; ++nj) {
            int col = n0 + wc * 32 + nj * 16 + c_lin;
            float bv = (col < Nreal) ? bpe[col] : 0.f;
            float ev = (col < Nreal) ? encb[col] : 0.f;
#pragma unroll
            for (int i = 0; i < 4; ++i) {
                int row = rowb + i;
                float v = acc[mi][nj][i] + bv;
                v = meta[row * 6 + 3] ? v : ev;
                if (col >= Nreal) v = 0.f;
                X[(size_t)row * ldx + col] = f2b(v);
            }
        }
    }
}

// ===== T1: pack (0..255) | G12 -> xA[:,768:1536] (256..303) — R7-verified =====
__global__ __launch_bounds__(256, 2) void pack_g12_k(
    const float* __restrict__ part, const int* __restrict__ meta,
    unsigned short* __restrict__ xA,
    const unsigned short* __restrict__ citA, const unsigned short* __restrict__ WpeT,
    const float* __restrict__ bpe, const float* __restrict__ encb) {
    __shared__ __align__(16) unsigned short As[2][8192];
    __shared__ __align__(16) unsigned short Bs[2][8192];
    int bid = blockIdx.x, tid = threadIdx.x;
    if (bid < 256) {
        if (tid >= 192) return;
        int b = bid;
        const float* p = part + (size_t)b * 8 * 768 + tid * 4;
        f32x4 m = *(const f32x4*)p;
#pragma unroll
        for (int ch = 1; ch < 8; ++ch) {
            f32x4 v = *(const f32x4*)(p + (size_t)ch * 768);
#pragma unroll
            for (int j = 0; j < 4; ++j) m[j] = fmaxf(m[j], v[j]);
        }
        if (!meta[b * 6 + 4]) {
            f32x4 z = {0.f, 0.f, 0.f, 0.f};
            m = z;
        }
        u16x4 o;
#pragma unroll
        for (int j = 0; j < 4; ++j) o[j] = f2b(m[j]);
        *(u16x4*)(xA + (size_t)b * 1536 + tid * 4) = o;
        return;
    }
    int r = bid - 256;
    g12_body(citA, WpeT, bpe, encb, meta, xA + 768, r % 12, r / 12, &As[0][0], &Bs[0][0]);
}

// ================= R4/R9-verified GEMM: BK=128, dbuf, gload_lds both sides =================
template<int EPI>   // 2 = relu(+bias)
__global__ __launch_bounds__(256, 2) void gemm_k(
    const unsigned short* __restrict__ A, int lda,
    const unsigned short* __restrict__ Bt, int ldb,
    const float* __restrict__ bias, const int* __restrict__ meta,
    unsigned short* __restrict__ X, int ldx, int Nreal, int Kp) {
    __shared__ __align__(16) unsigned short As[2][8192];
    __shared__ __align__(16) unsigned short Bs[2][8192];
    unsigned short* AsB = &As[0][0];
    unsigned short* BsB = &Bs[0][0];
    const int tid = threadIdx.x;
    const int wid = tid >> 6, lane = tid & 63;
    const int m0 = blockIdx.y * 64, n0 = blockIdx.x * 64;
    const int wr = wid >> 1, wc = wid & 1;
    const int c_lin = lane & 15;
    const int rsub = lane >> 4;

    int aoff[4], boff[4], ldst[4];
#pragma unroll
    for (int i = 0; i < 4; ++i) {
        int r = wid * 16 + i * 4 + rsub;
        int csrc = (c_lin ^ (r & 15)) << 3;
        aoff[i] = (m0 + r) * lda + csrc;
        boff[i] = (n0 + r) * ldb + csrc;
        ldst[i] = (wid * 16 + i * 4) * 128;
    }
    int cswz[4];
#pragma unroll
    for (int ks = 0; ks < 4; ++ks) cswz[ks] = ((ks * 4 + rsub) ^ c_lin) << 3;
    int arow[2], brow[2];
#pragma unroll
    for (int mi = 0; mi < 2; ++mi) arow[mi] = (wr * 32 + mi * 16 + c_lin) * 128;
#pragma unroll
    for (int nj = 0; nj < 2; ++nj) brow[nj] = (wc * 32 + nj * 16 + c_lin) * 128;

    f32x4 acc[2][2];
    const f32x4 zero = {0.f, 0.f, 0.f, 0.f};
#pragma unroll
    for (int mi = 0; mi < 2; ++mi)
#pragma unroll
        for (int nj = 0; nj < 2; ++nj) acc[mi][nj] = zero;

    auto stage = [&](int nb, int kt) {
#pragma unroll
        for (int i = 0; i < 4; ++i) load_lds16(A + aoff[i] + kt, AsB + nb * 8192 + ldst[i]);
#pragma unroll
        for (int i = 0; i < 4; ++i) load_lds16(Bt + boff[i] + kt, BsB + nb * 8192 + ldst[i]);
    };

    const int nt = Kp >> 7;
    stage(0, 0);
    int cb = 0;
    for (int t = 0; t < nt; ++t) {
        __syncthreads();
        if (t + 1 < nt) stage(cb ^ 1, (t + 1) << 7);
        const unsigned short* as = AsB + cb * 8192;
        const unsigned short* bs = BsB + cb * 8192;
#pragma unroll
        for (int ks = 0; ks < 4; ++ks) {
            bf16x8 af[2], bfr[2];
#pragma unroll
            for (int mi = 0; mi < 2; ++mi) af[mi] = *(const bf16x8*)(as + arow[mi] + cswz[ks]);
#pragma unroll
            for (int nj = 0; nj < 2; ++nj) bfr[nj] = *(const bf16x8*)(bs + brow[nj] + cswz[ks]);
#pragma unroll
            for (int mi = 0; mi < 2; ++mi)
#pragma unroll
                for (int nj = 0; nj < 2; ++nj)
                    acc[mi][nj] = __builtin_amdgcn_mfma_f32_16x16x32_bf16(
                        af[mi], bfr[nj], acc[mi][nj], 0, 0, 0);
        }
        cb ^= 1;
    }
#pragma unroll
    for (int mi = 0; mi < 2; ++mi) {
        int rowb = m0 + wr * 32 + mi * 16 + rsub * 4;
#pragma unroll
        for (int nj = 0; nj < 2; ++nj) {
            int col = n0 + wc * 32 + nj * 16 + c_lin;
            float bv = (col < Nreal) ? bias[col] : 0.f;
#pragma unroll
            for (int i = 0; i < 4; ++i) {
                int row = rowb + i;
                float v = acc[mi][nj][i] + bv;
                if (EPI == 0) v *= (meta[row * 6 + 3] ? 1.f : 0.f);
                if (EPI == 2) v = fmaxf(v, 0.f);
                if (col >= Nreal) v = 0.f;
                X[(size_t)row * ldx + col] = f2b(v);
            }
        }
    }
}

// ================= T4: out[b][j] = x2[b,:] . w3[:,j] + b3[j] =================
__global__ __launch_bounds__(256) void out_k(const unsigned short* __restrict__ x2,
                                             const float* __restrict__ w3,
                                             const float* __restrict__ b3,
                                             float* __restrict__ out) {
    int b = blockIdx.x, t = threadIdx.x;
    int wid = t >> 6, lane = t & 63;
    float s[6] = {0.f, 0.f, 0.f, 0.f, 0.f, 0.f};
    const unsigned short* xr = x2 + (size_t)b * 3072;
    for (int k = t; k < 3036; k += 256) {
        float x = b2f(xr[k]);
#pragma unroll
        for (int j = 0; j < 6; ++j) s[j] += x * w3[(size_t)k * 6 + j];
    }
#pragma unroll
    for (int j = 0; j < 6; ++j)
        for (int off = 1; off < 64; off <<= 1) s[j] += __shfl_xor(s[j], off);
    __shared__ float red[4][6];
    if (lane == 0) {
#pragma unroll
        for (int j = 0; j < 6; ++j) red[wid][j] = s[j];
    }
    __syncthreads();
    if (t < 6) out[b * 6 + t] = red[0][t] + red[1][t] + red[2][t] + red[3][t] + b3[t];
}

extern "C" void kernel_launch(void* const* d_in, const int* in_sizes, int n_in,
                              void* d_out, int out_size, void* d_ws, size_t ws_size,
                              hipStream_t stream) {
    const int*   tokens = (const int*)d_in[0];
    const float* hs     = (const float*)d_in[1];
    const float* proj_w = (const float*)d_in[2];
    const float* proj_b = (const float*)d_in[3];
    const float* enc_w  = (const float*)d_in[4];
    const float* enc_b  = (const float*)d_in[5];
    const float* w1 = (const float*)d_in[6];
    const float* b1 = (const float*)d_in[7];
    const float* w2 = (const float*)d_in[8];
    const float* b2 = (const float*)d_in[9];
    const float* w3 = (const float*)d_in[10];
    const float* b3 = (const float*)d_in[11];
    float* out = (float*)d_out;

    char* ws = (char*)d_ws;
    size_t off = 0;
    auto alloc = [&](size_t bytes) {
        void* p = ws + off;
        off = (off + bytes + 255) & ~(size_t)255;
        return p;
    };
    int* meta            = (int*)alloc(256 * 6 * sizeof(int));
    float* part          = (float*)alloc((size_t)256 * 8 * 768 * sizeof(float));
    unsigned short* xA   = (unsigned short*)alloc((size_t)256 * 1536 * 2);
    unsigned short* citA = (unsigned short*)alloc((size_t)256 * 768 * 2);
    unsigned short* x1   = (unsigned short*)alloc((size_t)256 * 3072 * 2);
    unsigned short* x2   = (unsigned short*)alloc((size_t)256 * 3072 * 2);
    unsigned short* WpeT = (unsigned short*)alloc((size_t)768 * 768 * 2);
    float* bpe           = (float*)alloc(768 * sizeof(float));
    unsigned short* w1T  = (unsigned short*)alloc((size_t)3072 * 1536 * 2);
    unsigned short* w2T  = (unsigned short*)alloc((size_t)3072 * 3072 * 2);

    // L0: W_pe = (proj @ enc)^T (input-only; isolated high-VGPR launch)
    l0_wpe_k<<<144, 256, 0, stream>>>(proj_w, enc_w, WpeT);
    // L1: pool + scan + cit + bpe + w1T/w2T (low VGPR, full occupancy)
    pool_mega_k<<<L1_TOTAL, 256, 0, stream>>>(tokens, hs, meta, citA, part,
                                              proj_b, enc_w, enc_b, w1, w2,
                                              bpe, w1T, w2T);
    // T1: pack xA[:,0:768] || G12 -> xA[:,768:1536]
    pack_g12_k<<<304, 256, 0, stream>>>(part, meta, xA, citA, WpeT, bpe, enc_b);
    // T2: x1 = relu(xA @ w1 + b1)
    gemm_k<2><<<dim3(48, 4), 256, 0, stream>>>(xA, 1536, w1T, 1536, b1, meta,
                                               x1, 3072, 3036, 1536);
    // T3: x2 = relu(x1 @ w2 + b2)
    gemm_k<2><<<dim3(48, 4), 256, 0, stream>>>(x1, 3072, w2T, 3072, b2, meta,
                                               x2, 3072, 3036, 3072);
    // T4
    out_k<<<256, 256, 0, stream>>>(x2, w3, b3, out);
}

// Round 13
// 152.597 us; speedup vs baseline: 1.3367x; 1.3367x over previous
//
#include <hip/hip_runtime.h>
#include <hip/hip_bf16.h>

typedef __attribute__((ext_vector_type(8))) short bf16x8;
typedef __attribute__((ext_vector_type(4))) float f32x4;
typedef __attribute__((ext_vector_type(4))) unsigned short u16x4;

#define NEGINF (-3.4028234663852886e38f)
#define BIGP (1 << 20)

__device__ __forceinline__ unsigned short f2b(float f) {
    union { float f; unsigned u; } x; x.f = f;
    unsigned r = x.u + 0x7FFFu + ((x.u >> 16) & 1u);
    return (unsigned short)(r >> 16);
}
__device__ __forceinline__ float b2f(unsigned short b) {
    union { unsigned u; float f; } x; x.u = ((unsigned)b) << 16;
    return x.f;
}
__device__ __forceinline__ void load_lds16(const void* g, void* l) {
    __builtin_amdgcn_global_load_lds((const __attribute__((address_space(1))) void*)g,
                                     (__attribute__((address_space(3))) void*)l, 16, 0, 0);
}

// ================= transpose tile 32x32, 8B stores (R4-verified) =================
__device__ __forceinline__ void trans32(const float* __restrict__ in, int K, int N,
                                        unsigned short* __restrict__ out, int ldo,
                                        int bx, int by, int tid, float (*tile)[33]) {
    int n0 = bx * 32, k0 = by * 32;
    int tx = tid & 31, ty = tid >> 5;
#pragma unroll
    for (int i = 0; i < 4; ++i) {
        int k = k0 + ty * 4 + i, n = n0 + tx;
        tile[ty * 4 + i][tx] = (k < K && n < N) ? in[(size_t)k * N + n] : 0.f;
    }
    __syncthreads();
    int n = tid >> 3, kc = tid & 7;
    u16x4 o;
#pragma unroll
    for (int q = 0; q < 4; ++q) o[q] = f2b(tile[kc * 4 + q][n]);
    *(u16x4*)(out + (size_t)(n0 + n) * ldo + k0 + kc * 4) = o;
}

// ===== L1 (R9-verified): pool(0..2047, inline scan) | scan(2048..2111) | cit(2112..2367) |
//           projT(2368..2943) | encT(2944..3519) | w1T(3520..8127) | w2T(8128..17343) =====
__global__ __launch_bounds__(256) void pool_mega_k(
    const int* __restrict__ tokens, const float* __restrict__ hs,
    int* __restrict__ meta, unsigned short* __restrict__ citA,
    float* __restrict__ part,
    const float* __restrict__ proj_w, const float* __restrict__ enc_w,
    const float* __restrict__ w1, const float* __restrict__ w2,
    unsigned short* __restrict__ projT, unsigned short* __restrict__ encT,
    unsigned short* __restrict__ w1T, unsigned short* __restrict__ w2T) {
    __shared__ float tile[32][33];
    int bid = blockIdx.x, tid = threadIdx.x;
    if (bid < 2048) {
        // pool with inline '@' ballot scan (R6/R8/R9-verified)
        if (tid >= 192) return;
        int b = bid >> 3, ch = bid & 7;
        int lane = tid & 63;
        const int* row = tokens + (size_t)b * 512;
        int first = BIGP, second = BIGP;
#pragma unroll
        for (int c = 0; c < 8; ++c) {
            int tok = row[c * 64 + lane];
            unsigned long long m = __ballot(tok == 5);
            if (m) {
                int base = c * 64;
                if (first == BIGP) {
                    first = base + (int)__ffsll(m) - 1;
                    unsigned long long m2 = m & (m - 1);
                    if (m2) second = base + (int)__ffsll(m2) - 1;
                } else if (second == BIGP) {
                    second = base + (int)__ffsll(m) - 1;
                }
            }
        }
        int start, end;
        if (second < BIGP) { start = first; end = second; }
        else               { start = 0;     end = 512;    }
        f32x4 m = { NEGINF, NEGINF, NEGINF, NEGINF };
        const float* basep = hs + (size_t)b * 512 * 768 + tid * 4;
        int s0 = ch * 64, hi = s0 + 64;
        int e1 = min(start, hi);
        int s2 = max(end + 1, s0);
#pragma unroll 4
        for (int s = s0; s < e1; ++s) {
            f32x4 v = *(const f32x4*)(basep + (size_t)s * 768);
#pragma unroll
            for (int j = 0; j < 4; ++j) m[j] = fmaxf(m[j], v[j]);
        }
#pragma unroll 4
        for (int s = s2; s < hi; ++s) {
            f32x4 v = *(const f32x4*)(basep + (size_t)s * 768);
#pragma unroll
            for (int j = 0; j < 4; ++j) m[j] = fmaxf(m[j], v[j]);
        }
        *(f32x4*)(part + ((size_t)b * 8 + ch) * 768 + tid * 4) = m;
        return;
    }
    if (bid < 2112) {
        // meta scan: one wave per batch row (R4-verified)
        const int S = 512;
        int b = (bid - 2048) * 4 + (tid >> 6), l = tid & 63;
        const int* row = tokens + (size_t)b * S;
        int base = l * 8;
        int toks[8];
#pragma unroll
        for (int i = 0; i < 8; ++i) toks[i] = row[base + i];
        int am = 0, cnt = 0, minAt = BIGP, minC = BIGP;
#pragma unroll
        for (int i = 0; i < 8; ++i) {
            if (toks[i] == 5) { am |= 1 << i; cnt++; if (base + i < minAt) minAt = base + i; }
            if (toks[i] == 7) { if (base + i < minC) minC = base + i; }
        }
        for (int off = 1; off < 64; off <<= 1) {
            minAt = min(minAt, __shfl_xor(minAt, off));
            minC  = min(minC,  __shfl_xor(minC,  off));
            cnt  += __shfl_xor(cnt, off);
        }
        int first = minAt, minAt2 = BIGP;
#pragma unroll
        for (int i = 0; i < 8; ++i)
            if ((am >> i) & 1) { int idx = base + i; if (idx > first && idx < minAt2) minAt2 = idx; }
        for (int off = 1; off < 64; off <<= 1) minAt2 = min(minAt2, __shfl_xor(minAt2, off));
        if (l == 0) {
            int ge2 = (cnt >= 2) ? 1 : 0;
            int start = ge2 ? first : 0;
            int end = ge2 ? minAt2 : S;
            int anyKeep = (ge2 && (start > 0 || end < S - 1)) ? 1 : 0;
            int has_c = (minC < S) ? 1 : 0;
            int cpos = min(minC, S - 1);
            int* m = meta + b * 6;
            m[0] = start; m[1] = end; m[2] = cpos; m[3] = has_c; m[4] = anyKeep; m[5] = 0;
        }
        return;
    }
    if (bid < 2368) {
        // cit gather with inline CITSEG ballot scan (R6/R9-verified)
        if (tid >= 192) return;
        int b = bid - 2112, lane = tid & 63;
        const int* row = tokens + (size_t)b * 512;
        int minC = BIGP;
#pragma unroll
        for (int c = 0; c < 8; ++c) {
            int tok = row[c * 64 + lane];
            unsigned long long m = __ballot(tok == 7);
            if (minC == BIGP && m) minC = c * 64 + (int)__ffsll(m) - 1;
        }
        int cpos = min(minC, 511);
        f32x4 cv = *(const f32x4*)(hs + ((size_t)b * 512 + cpos) * 768 + tid * 4);
        u16x4 co;
#pragma unroll
        for (int j = 0; j < 4; ++j) co[j] = f2b(cv[j]);
        *(u16x4*)(citA + (size_t)b * 768 + tid * 4) = co;
        return;
    }
    int r = bid - 2368;
    if (r < 576)  { trans32(proj_w, 768, 750, projT, 768, r % 24, r / 24, tid, tile); return; }
    r -= 576;
    if (r < 576)  { trans32(enc_w, 750, 750, encT, 768, r % 24, r / 24, tid, tile); return; }
    r -= 576;
    if (r < 4608) { trans32(w1, 1518, 3036, w1T, 1536, r % 96, r / 96, tid, tile); return; }
    r -= 4608;
    trans32(w2, 3036, 3036, w2T, 3072, r % 96, r / 96, tid, tile);
}

// ================= R4-verified GEMM body: BK=128, dbuf, gload_lds both sides =================
// EPI: 0=(+bias)*has_c  1=+bias  2=relu(+bias)
template<int EPI>
__device__ __forceinline__ void gemm_body(
    const unsigned short* __restrict__ A, int lda,
    const unsigned short* __restrict__ Bt, int ldb,
    const float* __restrict__ bias, const int* __restrict__ meta,
    unsigned short* __restrict__ X, int ldx, int Nreal, int Kp,
    int bx, int by, unsigned short* AsB, unsigned short* BsB) {
    const int tid = threadIdx.x;
    const int wid = tid >> 6, lane = tid & 63;
    const int m0 = by * 64, n0 = bx * 64;
    const int wr = wid >> 1, wc = wid & 1;
    const int c_lin = lane & 15;
    const int rsub = lane >> 4;

    int aoff[4], boff[4], ldst[4];
#pragma unroll
    for (int i = 0; i < 4; ++i) {
        int r = wid * 16 + i * 4 + rsub;
        int csrc = (c_lin ^ (r & 15)) << 3;
        aoff[i] = (m0 + r) * lda + csrc;
        boff[i] = (n0 + r) * ldb + csrc;
        ldst[i] = (wid * 16 + i * 4) * 128;
    }
    int cswz[4];
#pragma unroll
    for (int ks = 0; ks < 4; ++ks) cswz[ks] = ((ks * 4 + rsub) ^ c_lin) << 3;
    int arow[2], brow[2];
#pragma unroll
    for (int mi = 0; mi < 2; ++mi) arow[mi] = (wr * 32 + mi * 16 + c_lin) * 128;
#pragma unroll
    for (int nj = 0; nj < 2; ++nj) brow[nj] = (wc * 32 + nj * 16 + c_lin) * 128;

    f32x4 acc[2][2];
    const f32x4 zero = {0.f, 0.f, 0.f, 0.f};
#pragma unroll
    for (int mi = 0; mi < 2; ++mi)
#pragma unroll
        for (int nj = 0; nj < 2; ++nj) acc[mi][nj] = zero;

    auto stage = [&](int nb, int kt) {
#pragma unroll
        for (int i = 0; i < 4; ++i) load_lds16(A + aoff[i] + kt, AsB + nb * 8192 + ldst[i]);
#pragma unroll
        for (int i = 0; i < 4; ++i) load_lds16(Bt + boff[i] + kt, BsB + nb * 8192 + ldst[i]);
    };

    const int nt = Kp >> 7;
    stage(0, 0);
    int cb = 0;
    for (int t = 0; t < nt; ++t) {
        __syncthreads();
        if (t + 1 < nt) stage(cb ^ 1, (t + 1) << 7);
        const unsigned short* as = AsB + cb * 8192;
        const unsigned short* bs = BsB + cb * 8192;
#pragma unroll
        for (int ks = 0; ks < 4; ++ks) {
            bf16x8 af[2], bfr[2];
#pragma unroll
            for (int mi = 0; mi < 2; ++mi) af[mi] = *(const bf16x8*)(as + arow[mi] + cswz[ks]);
#pragma unroll
            for (int nj = 0; nj < 2; ++nj) bfr[nj] = *(const bf16x8*)(bs + brow[nj] + cswz[ks]);
#pragma unroll
            for (int mi = 0; mi < 2; ++mi)
#pragma unroll
                for (int nj = 0; nj < 2; ++nj)
                    acc[mi][nj] = __builtin_amdgcn_mfma_f32_16x16x32_bf16(
                        af[mi], bfr[nj], acc[mi][nj], 0, 0, 0);
        }
        cb ^= 1;
    }
#pragma unroll
    for (int mi = 0; mi < 2; ++mi) {
        int rowb = m0 + wr * 32 + mi * 16 + rsub * 4;
#pragma unroll
        for (int nj = 0; nj < 2; ++nj) {
            int col = n0 + wc * 32 + nj * 16 + c_lin;
            float bv = (col < Nreal) ? bias[col] : 0.f;
#pragma unroll
            for (int i = 0; i < 4; ++i) {
                int row = rowb + i;
                float v = acc[mi][nj][i] + bv;
                if (EPI == 0) v *= (meta[row * 6 + 3] ? 1.f : 0.f);
                if (EPI == 2) v = fmaxf(v, 0.f);
                if (col >= Nreal) v = 0.f;
                X[(size_t)row * ldx + col] = f2b(v);
            }
        }
    }
}

// ================= L2: pack (256 blocks) + G1 (48 blocks) — R4/R9-verified =================
__global__ __launch_bounds__(256, 2) void pack_g1_k(
    const float* __restrict__ part, const int* __restrict__ meta,
    unsigned short* __restrict__ xA,
    const unsigned short* __restrict__ citA, const unsigned short* __restrict__ projT,
    const float* __restrict__ proj_b, unsigned short* __restrict__ citB) {
    __shared__ __align__(16) unsigned short As[2][8192];
    __shared__ __align__(16) unsigned short Bs[2][8192];
    int bid = blockIdx.x, tid = threadIdx.x;
    if (bid < 256) {
        if (tid >= 192) return;
        int b = bid;
        const float* p = part + (size_t)b * 8 * 768 + tid * 4;
        f32x4 m = *(const f32x4*)p;
#pragma unroll
        for (int ch = 1; ch < 8; ++ch) {
            f32x4 v = *(const f32x4*)(p + (size_t)ch * 768);
#pragma unroll
            for (int j = 0; j < 4; ++j) m[j] = fmaxf(m[j], v[j]);
        }
        if (!meta[b * 6 + 4]) {
            f32x4 z = {0.f, 0.f, 0.f, 0.f};
            m = z;
        }
        u16x4 o;
#pragma unroll
        for (int j = 0; j < 4; ++j) o[j] = f2b(m[j]);
        *(u16x4*)(xA + (size_t)b * 1536 + tid * 4) = o;
        return;
    }
    int r = bid - 256;  // 0..47 -> G1: [256x768]x[768x750]
    gemm_body<0>(citA, 768, projT, 768, proj_b, meta, citB, 768, 750, 768,
                 r % 12, r / 12, &As[0][0], &Bs[0][0]);
}

// ================= standalone GEMM kernels (R4/R9-verified) =================
template<int EPI>
__global__ __launch_bounds__(256, 2) void gemm_k(
    const unsigned short* __restrict__ A, int lda,
    const unsigned short* __restrict__ Bt, int ldb,
    const float* __restrict__ bias, const int* __restrict__ meta,
    unsigned short* __restrict__ X, int ldx, int Nreal, int Kp) {
    __shared__ __align__(16) unsigned short As[2][8192];
    __shared__ __align__(16) unsigned short Bs[2][8192];
    gemm_body<EPI>(A, lda, Bt, ldb, bias, meta, X, ldx, Nreal, Kp,
                   blockIdx.x, blockIdx.y, &As[0][0], &Bs[0][0]);
}

// ================= L6: out[b][j] = x2[b,:] . w3[:,j] + b3[j] =================
__global__ __launch_bounds__(256) void out_k(const unsigned short* __restrict__ x2,
                                             const float* __restrict__ w3,
                                             const float* __restrict__ b3,
                                             float* __restrict__ out) {
    int b = blockIdx.x, t = threadIdx.x;
    int wid = t >> 6, lane = t & 63;
    float s[6] = {0.f, 0.f, 0.f, 0.f, 0.f, 0.f};
    const unsigned short* xr = x2 + (size_t)b * 3072;
    for (int k = t; k < 3036; k += 256) {
        float x = b2f(xr[k]);
#pragma unroll
        for (int j = 0; j < 6; ++j) s[j] += x * w3[(size_t)k * 6 + j];
    }
#pragma unroll
    for (int j = 0; j < 6; ++j)
        for (int off = 1; off < 64; off <<= 1) s[j] += __shfl_xor(s[j], off);
    __shared__ float red[4][6];
    if (lane == 0) {
#pragma unroll
        for (int j = 0; j < 6; ++j) red[wid][j] = s[j];
    }
    __syncthreads();
    if (t < 6) out[b * 6 + t] = red[0][t] + red[1][t] + red[2][t] + red[3][t] + b3[t];
}

extern "C" void kernel_launch(void* const* d_in, const int* in_sizes, int n_in,
                              void* d_out, int out_size, void* d_ws, size_t ws_size,
                              hipStream_t stream) {
    const int*   tokens = (const int*)d_in[0];
    const float* hs     = (const float*)d_in[1];
    const float* proj_w = (const float*)d_in[2];
    const float* proj_b = (const float*)d_in[3];
    const float* enc_w  = (const float*)d_in[4];
    const float* enc_b  = (const float*)d_in[5];
    const float* w1 = (const float*)d_in[6];
    const float* b1 = (const float*)d_in[7];
    const float* w2 = (const float*)d_in[8];
    const float* b2 = (const float*)d_in[9];
    const float* w3 = (const float*)d_in[10];
    const float* b3 = (const float*)d_in[11];
    float* out = (float*)d_out;

    char* ws = (char*)d_ws;
    size_t off = 0;
    auto alloc = [&](size_t bytes) {
        void* p = ws + off;
        off = (off + bytes + 255) & ~(size_t)255;
        return p;
    };
    int* meta            = (int*)alloc(256 * 6 * sizeof(int));
    float* part          = (float*)alloc((size_t)256 * 8 * 768 * sizeof(float));
    unsigned short* xA   = (unsigned short*)alloc((size_t)256 * 1536 * 2);
    unsigned short* citA = (unsigned short*)alloc((size_t)256 * 768 * 2);
    unsigned short* citB = (unsigned short*)alloc((size_t)256 * 768 * 2);
    unsigned short* x1   = (unsigned short*)alloc((size_t)256 * 3072 * 2);
    unsigned short* x2   = (unsigned short*)alloc((size_t)256 * 3072 * 2);
    unsigned short* projT= (unsigned short*)alloc((size_t)768 * 768 * 2);
    unsigned short* encT = (unsigned short*)alloc((size_t)768 * 768 * 2);
    unsigned short* w1T  = (unsigned short*)alloc((size_t)3072 * 1536 * 2);
    unsigned short* w2T  = (unsigned short*)alloc((size_t)3072 * 3072 * 2);

    // L1: scan + cit + pool + all transposes (one wide low-VGPR launch, R8/R9-verified)
    pool_mega_k<<<17344, 256, 0, stream>>>(tokens, hs, meta, citA, part,
                                           proj_w, enc_w, w1, w2,
                                           projT, encT, w1T, w2T);
    // L2: pack + G1
    pack_g1_k<<<304, 256, 0, stream>>>(part, meta, xA, citA, projT, proj_b, citB);
    // L3: G2 -> xA[:,768:1518]
    gemm_k<1><<<dim3(12, 4), 256, 0, stream>>>(citB, 768, encT, 768, enc_b, meta,
                                               xA + 768, 1536, 750, 768);
    // L4: G3
    gemm_k<2><<<dim3(48, 4), 256, 0, stream>>>(xA, 1536, w1T, 1536, b1, meta,
                                               x1, 3072, 3036, 1536);
    // L5: G4
    gemm_k<2><<<dim3(48, 4), 256, 0, stream>>>(x1, 3072, w2T, 3072, b2, meta,
                                               x2, 3072, 3036, 3072);
    // L6
    out_k<<<256, 256, 0, stream>>>(x2, w3, b3, out);
}